// Round 10
// baseline (452.023 us; speedup 1.0000x reference)
//
#include <hip/hip_runtime.h>
#include <math.h>

// ---- fixed problem sizes ----
#define NTOK 1024
#define DDIM 1024
#define HEADS 16
#define KVH 4
#define DH 64
#define BSZ 32
#define NSEL 8
#define WBLK 32            // NTOK / BSZ
#define GQ 4               // HEADS / KVH
#define CDIM 2048          // BSZ*DH
#define HIDN 2048
#define QKVD 1536          // (HEADS + 2*KVH)*DH
#define SCALE 0.125f       // DH^-0.5
#define NEGINF (-__builtin_inff())

typedef unsigned short u16;
typedef u16   u16x8  __attribute__((ext_vector_type(8)));
typedef short short8 __attribute__((ext_vector_type(8)));
typedef float f32x4  __attribute__((ext_vector_type(4)));

__device__ __forceinline__ u16 f2bf(float f) {
    unsigned u = __float_as_uint(f);
    return (u16)((u + 0x7fffu + ((u >> 16) & 1u)) >> 16);
}
__device__ __forceinline__ float bf2f(u16 h) { return __uint_as_float(((unsigned)h) << 16); }

__device__ __forceinline__ void glds16(const void* g, void* l) {
    __builtin_amdgcn_global_load_lds(
        (const __attribute__((address_space(1))) unsigned int*)g,
        (__attribute__((address_space(3))) unsigned int*)l, 16, 0, 0);
}

// element offset (in u16) of the 8-element lane-slot for (row, k..k+7) in the
// MFMA-fragment-tiled layout: 16-row x 32-k tiles, 1KB each, contiguous.
__device__ __forceinline__ size_t tiled_off(int row, int k, int K) {
    return ((size_t)((row >> 4) * (K >> 5) + (k >> 5)) * 64 +
            ((row & 15) | (((k >> 3) & 3) << 4))) * 8;
}

// ---------------------------------------------------------------------------
// K1: RMSNorm -> split-bf16 x in TILED layout (K=DDIM). 2 rows per 256-thr block.
// ---------------------------------------------------------------------------
__global__ void rmsnorm_kernel(const float* __restrict__ inp, const float* __restrict__ g,
                               u16* __restrict__ xhi, u16* __restrict__ xlo) {
    int t = threadIdx.x;
    int half = t >> 7, tid = t & 127;
    int n = blockIdx.x * 2 + half;
    const float4* row = (const float4*)(inp + (size_t)n * DDIM);
    float4 v0 = row[tid * 2], v1 = row[tid * 2 + 1];
    float ss = v0.x*v0.x + v0.y*v0.y + v0.z*v0.z + v0.w*v0.w
             + v1.x*v1.x + v1.y*v1.y + v1.z*v1.z + v1.w*v1.w;
    for (int off = 32; off; off >>= 1) ss += __shfl_down(ss, off);
    __shared__ float red[4];
    if ((t & 63) == 0) red[t >> 6] = ss;
    __syncthreads();
    float tot = red[half * 2] + red[half * 2 + 1];
    float r = 1.f / sqrtf(tot * (1.f / DDIM) + 1e-6f);
    const float4* gp = (const float4*)g;
    float4 g0 = gp[tid * 2], g1 = gp[tid * 2 + 1];
    float o[8] = { v0.x*r*g0.x, v0.y*r*g0.y, v0.z*r*g0.z, v0.w*r*g0.w,
                   v1.x*r*g1.x, v1.y*r*g1.y, v1.z*r*g1.z, v1.w*r*g1.w };
    u16x8 h, l;
#pragma unroll
    for (int i = 0; i < 8; ++i) {
        u16 hh = f2bf(o[i]);
        h[i] = hh;
        l[i] = f2bf(o[i] - bf2f(hh));
    }
    size_t ob = tiled_off(n, tid * 8, DDIM);
    *(u16x8*)&xhi[ob] = h;
    *(u16x8*)&xlo[ob] = l;
}

// ---------------------------------------------------------------------------
// K2: merged weight transpose+split for all 4 big weights (1 launch).
// W[K][N] f32 -> tiled Bt[N][K] bf16 hi/lo. Block-range routing.
// ---------------------------------------------------------------------------
__global__ void prep_weights(const float* __restrict__ wq,  u16* __restrict__ wqhi,  u16* __restrict__ wqlo,
                             const float* __restrict__ kw1, u16* __restrict__ k1hi, u16* __restrict__ k1lo,
                             const float* __restrict__ vw1, u16* __restrict__ v1hi, u16* __restrict__ v1lo,
                             const float* __restrict__ wo,  u16* __restrict__ wohi) {
    int b = blockIdx.x;
    const float* W; u16 *Thi, *Tlo; int K, N, bx, by;
    if (b < 384)       { W = wq;  Thi = wqhi; Tlo = wqlo; K = DDIM; N = QKVD; int r = b;        bx = r % 24; by = r / 24; }
    else if (b < 1408) { W = kw1; Thi = k1hi; Tlo = k1lo; K = CDIM; N = HIDN; int r = b - 384;  bx = r % 32; by = r / 32; }
    else if (b < 2432) { W = vw1; Thi = v1hi; Tlo = v1lo; K = CDIM; N = HIDN; int r = b - 1408; bx = r % 32; by = r / 32; }
    else               { W = wo;  Thi = wohi; Tlo = nullptr; K = DDIM; N = DDIM; int r = b - 2432; bx = r % 16; by = r / 16; }
    __shared__ float tile[64][65];
    int k0 = by * 64, n0 = bx * 64;
    int t = threadIdx.x;
    int r = t >> 4, c4 = (t & 15) * 4;
#pragma unroll
    for (int p = 0; p < 4; ++p) {
        float4 v = *(const float4*)&W[(size_t)(k0 + r + p * 16) * N + n0 + c4];
        tile[r + p * 16][c4 + 0] = v.x;
        tile[r + p * 16][c4 + 1] = v.y;
        tile[r + p * 16][c4 + 2] = v.z;
        tile[r + p * 16][c4 + 3] = v.w;
    }
    __syncthreads();
    int n = t >> 2, ks = (t & 3) * 16;
#pragma unroll
    for (int c = 0; c < 2; ++c) {
        u16x8 h, l;
#pragma unroll
        for (int j = 0; j < 8; ++j) {
            float v = tile[ks + c * 8 + j][n];
            u16 hh = f2bf(v);
            h[j] = hh;
            l[j] = f2bf(v - bf2f(hh));
        }
        size_t ob = tiled_off(n0 + n, k0 + ks + c * 8, K);
        *(u16x8*)&Thi[ob] = h;
        if (Tlo) *(u16x8*)&Tlo[ob] = l;
    }
}

// ---------------------------------------------------------------------------
// K2b: merged pad of the 3 small weights (1 launch; blockIdx.y routes).
// W[K][Xn] (Xn<=64) -> tiled split-bf16 [128][K] + padded bias.
// ---------------------------------------------------------------------------
__global__ void pad_all(const float* __restrict__ gw,  const float* __restrict__ gb,
                        u16* __restrict__ gwhi, u16* __restrict__ gwlo, float* __restrict__ gbp,
                        const float* __restrict__ kw2, const float* __restrict__ kb2,
                        u16* __restrict__ k2hi, u16* __restrict__ k2lo, float* __restrict__ kb2p,
                        const float* __restrict__ vw2, const float* __restrict__ vb2,
                        u16* __restrict__ v2hi, u16* __restrict__ v2lo, float* __restrict__ vb2p) {
    int which = blockIdx.y;
    const float *W, *b; u16 *Thi, *Tlo; float* bias_pad; int K, KLOG, Xn;
    if (which == 0) { W = gw;  b = gb;  Thi = gwhi; Tlo = gwlo; bias_pad = gbp;  K = DDIM; KLOG = 10; Xn = 32; }
    else if (which == 1) { W = kw2; b = kb2; Thi = k2hi; Tlo = k2lo; bias_pad = kb2p; K = HIDN; KLOG = 11; Xn = 64; }
    else { W = vw2; b = vb2; Thi = v2hi; Tlo = v2lo; bias_pad = vb2p; K = HIDN; KLOG = 11; Xn = 64; }
    int idx = blockIdx.x * 256 + threadIdx.x;
    if (idx >= 128 * (K >> 3)) return;
    int k = (idx & ((K >> 3) - 1)) * 8;
    int n = idx >> (KLOG - 3);
    if (n >= 128) return;
    u16x8 h, l;
#pragma unroll
    for (int j = 0; j < 8; ++j) {
        float v = (n < Xn) ? W[(size_t)(k + j) * Xn + n] : 0.f;
        u16 hh = f2bf(v);
        h[j] = hh;
        l[j] = f2bf(v - bf2f(hh));
    }
    size_t ob = tiled_off(n, k, K);
    *(u16x8*)&Thi[ob] = h;
    *(u16x8*)&Tlo[ob] = l;
    if (k == 0) bias_pad[n] = (n < Xn) ? b[n] : 0.f;
}

// ---------------------------------------------------------------------------
// K3: tiled MFMA GEMM with software pipeline + optional split-K.
// ---------------------------------------------------------------------------
template<int SPLIT, int ACT, int FINAL>
__global__ __launch_bounds__(256, 1)
void gemm_tiled(const u16* __restrict__ Ahi0, const u16* __restrict__ Alo0,
                const u16* __restrict__ Bhi0, const u16* __restrict__ Blo0,
                const float* __restrict__ bias0, float* __restrict__ C0,
                const u16* __restrict__ Ahi1, const u16* __restrict__ Alo1,
                const u16* __restrict__ Bhi1, const u16* __restrict__ Blo1,
                const float* __restrict__ bias1, float* __restrict__ C1,
                int M, int N, int K, int S) {
    int batch = blockIdx.z / S;
    int s = blockIdx.z - batch * S;
    const u16* Ahi = batch ? Ahi1 : Ahi0;
    const u16* Alo = batch ? Alo1 : Alo0;
    const u16* Bhi = batch ? Bhi1 : Bhi0;
    const u16* Blo = batch ? Blo1 : Blo0;
    const float* bias = batch ? bias1 : bias0;
    float* C = batch ? C1 : C0;

    constexpr int PARTS = (SPLIT == 3) ? 2 : 1;
    __shared__ u16 smA[2 * PARTS * 8 * 512];
    __shared__ u16 smB[2 * PARTS * 8 * 512];

    int tid = threadIdx.x;
    int w = tid >> 6, L = tid & 63;
    int m15 = L & 15, q = L >> 4;
    int KT = K >> 5;
    int rowTile = blockIdx.y * 8, colTile = blockIdx.x * 8;
    int NIT = (K / S) >> 5;
    int kb0 = s * NIT;
    int aw = w & 1, bw = w >> 1;

    f32x4 acc[4][4];
#pragma unroll
    for (int i = 0; i < 4; ++i)
#pragma unroll
        for (int j = 0; j < 4; ++j) acc[i][j] = (f32x4){0.f, 0.f, 0.f, 0.f};

    auto stage = [&](int buf, int kb) {
#pragma unroll
        for (int rl = 0; rl < 2; ++rl) {
            int rb = 2 * w + rl;
            glds16(Ahi + ((size_t)(rowTile + rb) * KT + kb) * 512 + (size_t)L * 8,
                   &smA[((buf * PARTS + 0) * 8 + rb) * 512]);
            glds16(Bhi + ((size_t)(colTile + rb) * KT + kb) * 512 + (size_t)L * 8,
                   &smB[((buf * PARTS + 0) * 8 + rb) * 512]);
            if constexpr (SPLIT == 3) {
                glds16(Alo + ((size_t)(rowTile + rb) * KT + kb) * 512 + (size_t)L * 8,
                       &smA[((buf * PARTS + 1) * 8 + rb) * 512]);
                glds16(Blo + ((size_t)(colTile + rb) * KT + kb) * 512 + (size_t)L * 8,
                       &smB[((buf * PARTS + 1) * 8 + rb) * 512]);
            }
        }
    };

    stage(0, kb0);
    for (int it = 0; it < NIT; ++it) {
        __syncthreads();
        if (it + 1 < NIT) stage((it + 1) & 1, kb0 + it + 1);
        int buf = it & 1;
        short8 ah[4], bh[4];
#pragma unroll
        for (int i = 0; i < 4; ++i) {
            ah[i] = *(const short8*)&smA[((buf * PARTS + 0) * 8 + aw * 4 + i) * 512 + L * 8];
            bh[i] = *(const short8*)&smB[((buf * PARTS + 0) * 8 + bw * 4 + i) * 512 + L * 8];
        }
        if constexpr (SPLIT == 3) {
            short8 al[4], bl[4];
#pragma unroll
            for (int i = 0; i < 4; ++i) {
                al[i] = *(const short8*)&smA[((buf * PARTS + 1) * 8 + aw * 4 + i) * 512 + L * 8];
                bl[i] = *(const short8*)&smB[((buf * PARTS + 1) * 8 + bw * 4 + i) * 512 + L * 8];
            }
#pragma unroll
            for (int i = 0; i < 4; ++i)
#pragma unroll
                for (int j = 0; j < 4; ++j) {
                    acc[i][j] = __builtin_amdgcn_mfma_f32_16x16x32_bf16(ah[i], bl[j], acc[i][j], 0, 0, 0);
                    acc[i][j] = __builtin_amdgcn_mfma_f32_16x16x32_bf16(al[i], bh[j], acc[i][j], 0, 0, 0);
                    acc[i][j] = __builtin_amdgcn_mfma_f32_16x16x32_bf16(ah[i], bh[j], acc[i][j], 0, 0, 0);
                }
        } else {
#pragma unroll
            for (int i = 0; i < 4; ++i)
#pragma unroll
                for (int j = 0; j < 4; ++j)
                    acc[i][j] = __builtin_amdgcn_mfma_f32_16x16x32_bf16(ah[i], bh[j], acc[i][j], 0, 0, 0);
        }
    }

    if constexpr (FINAL == 0) C += (size_t)s * M * N;
#pragma unroll
    for (int i = 0; i < 4; ++i) {
        int row = rowTile * 16 + aw * 64 + i * 16 + q * 4;
#pragma unroll
        for (int j = 0; j < 4; ++j) {
            int col = colTile * 16 + bw * 64 + j * 16 + m15;
            float bv = (FINAL && bias) ? bias[col] : 0.f;
#pragma unroll
            for (int r = 0; r < 4; ++r) {
                float v = acc[i][j][r];
                if constexpr (FINAL) {
                    v += bv;
                    if (ACT == 1) v = fmaxf(v, 0.f);
                    if (ACT == 2) v = 1.f / (1.f + expf(-v));
                }
                C[(size_t)(row + r) * N + col] = v;
            }
        }
    }
}

// ---------------------------------------------------------------------------
// K3b: split-K reduce -> f32 [M][N] with bias/act. Dual pointer sets via blockIdx.y.
// ---------------------------------------------------------------------------
template<int ACT>
__global__ void reduce_f32(const float* __restrict__ P0, const float* __restrict__ bias0,
                           float* __restrict__ C0,
                           const float* __restrict__ P1, const float* __restrict__ bias1,
                           float* __restrict__ C1, int S, int M, int N) {
    const float* P = blockIdx.y ? P1 : P0;
    const float* bias = blockIdx.y ? bias1 : bias0;
    float* C = blockIdx.y ? C1 : C0;
    int idx = blockIdx.x * 256 + threadIdx.x;
    int mn4 = (M * N) >> 2;
    if (idx >= mn4) return;
    f32x4 a = ((const f32x4*)P)[idx];
    for (int s = 1; s < S; ++s) a += ((const f32x4*)P)[(size_t)s * mn4 + idx];
    int col = (idx % (N >> 2)) * 4;
    f32x4 o;
#pragma unroll
    for (int j = 0; j < 4; ++j) {
        float v = a[j] + (bias ? bias[col + j] : 0.f);
        if (ACT == 1) v = fmaxf(v, 0.f);
        if (ACT == 2) v = 1.f / (1.f + expf(-v));
        o[j] = v;
    }
    ((f32x4*)C)[idx] = o;
}

// ---------------------------------------------------------------------------
// K3c: split-K reduce + relu + bias -> split-bf16 TILED (MLP1 hid, M=128, N=HIDN)
// ---------------------------------------------------------------------------
__global__ void reduce_hid(const float* __restrict__ P0, const float* __restrict__ b0,
                           u16* __restrict__ hi0, u16* __restrict__ lo0,
                           const float* __restrict__ P1, const float* __restrict__ b1,
                           u16* __restrict__ hi1, u16* __restrict__ lo1, int S) {
    const float* P = blockIdx.y ? P1 : P0;
    const float* bias = blockIdx.y ? b1 : b0;
    u16* hi = blockIdx.y ? hi1 : hi0;
    u16* lo = blockIdx.y ? lo1 : lo0;
    int idx = blockIdx.x * 256 + threadIdx.x;       // 128*2048/8 = 32768
    int col = (idx & 255) * 8, rowi = idx >> 8;
    size_t base = ((size_t)rowi * HIDN + col) >> 2;
    f32x4 a0 = ((const f32x4*)P)[base], a1 = ((const f32x4*)P)[base + 1];
    for (int s = 1; s < S; ++s) {
        size_t sb = (size_t)s * (128 * HIDN / 4) + base;
        a0 += ((const f32x4*)P)[sb];
        a1 += ((const f32x4*)P)[sb + 1];
    }
    u16x8 h, l;
#pragma unroll
    for (int j = 0; j < 8; ++j) {
        float v = (j < 4 ? a0[j] : a1[j - 4]) + bias[col + j];
        v = fmaxf(v, 0.f);
        u16 hh = f2bf(v);
        h[j] = hh;
        l[j] = f2bf(v - bf2f(hh));
    }
    size_t ob = tiled_off(rowi, col, HIDN);
    *(u16x8*)&hi[ob] = h;
    *(u16x8*)&lo[ob] = l;
}

// ---------------------------------------------------------------------------
// K3d: MLP2 split-K reduce + bias fused with mem_kv concat -> ck/cv [KVH][33][DH]
// ---------------------------------------------------------------------------
__global__ void reduce_ckcv(const float* __restrict__ Pk, const float* __restrict__ Pv,
                            const float* __restrict__ mem_kv,
                            const float* __restrict__ kb2, const float* __restrict__ vb2,
                            float* __restrict__ ck, float* __restrict__ cv, int S) {
    int idx = blockIdx.x * 256 + threadIdx.x;   // 4*33*64 = 8448
    if (idx >= KVH * 33 * DH) return;
    int d = idx & 63;
    int j = (idx >> 6) % 33;
    int h = idx / (33 * 64);
    float kvv, vvv;
    if (j == 0) {
        kvv = mem_kv[(0 * KVH + h) * DH + d];
        vvv = mem_kv[(1 * KVH + h) * DH + d];
    } else {
        size_t base = (size_t)(h * WBLK + (j - 1)) * 128 + d;
        float ak = Pk[base], av = Pv[base];
        for (int s = 1; s < S; ++s) {
            ak += Pk[(size_t)s * (128 * 128) + base];
            av += Pv[(size_t)s * (128 * 128) + base];
        }
        kvv = ak + kb2[d];
        vvv = av + vb2[d];
    }
    ck[idx] = kvv;
    cv[idx] = vvv;
}

// ---------------------------------------------------------------------------
// K5: build compress-MLP inputs -> split-bf16 TILED (K=CDIM)
// ---------------------------------------------------------------------------
__global__ void build_cmlp_in(const float* __restrict__ qkv, const float* __restrict__ k_pos,
                              const float* __restrict__ v_pos,
                              u16* __restrict__ ckhi, u16* __restrict__ cklo,
                              u16* __restrict__ cvhi, u16* __restrict__ cvlo) {
    int idx = blockIdx.x * 256 + threadIdx.x;   // 128 * 256 = 32768
    int k = (idx & 255) * 8;
    int r = idx >> 8;                           // 0..127 = h*W + w
    int p = k >> 6, d = k & 63;
    int h = r >> 5, wb = r & 31;
    int nn = wb * BSZ + p;
    const float* kq = qkv + (size_t)nn * QKVD + (HEADS + h) * DH + d;
    const float* vq = qkv + (size_t)nn * QKVD + (HEADS + KVH + h) * DH + d;
    const float* kp = k_pos + (size_t)(h * BSZ + p) * DH + d;
    const float* vp = v_pos + (size_t)(h * BSZ + p) * DH + d;
    u16x8 kh, kl, vh, vl;
#pragma unroll
    for (int j = 0; j < 8; ++j) {
        float kv = kq[j] + kp[j];
        float vv = vq[j] + vp[j];
        u16 a = f2bf(kv), b = f2bf(vv);
        kh[j] = a; kl[j] = f2bf(kv - bf2f(a));
        vh[j] = b; vl[j] = f2bf(vv - bf2f(b));
    }
    size_t ob = tiled_off(r, k, CDIM);
    *(u16x8*)&ckhi[ob] = kh; *(u16x8*)&cklo[ob] = kl;
    *(u16x8*)&cvhi[ob] = vh; *(u16x8*)&cvlo[ob] = vl;
}

// ---------------------------------------------------------------------------
// K7: interleaved rotary for q (16 heads), k (4 heads) + packed v copy (4 heads)
// ---------------------------------------------------------------------------
__global__ void rotary_kernel(const float* __restrict__ qkv,
                              float* __restrict__ qr, float* __restrict__ kr,
                              float* __restrict__ vr) {
    int idx = blockIdx.x * 256 + threadIdx.x;   // 24*1024*32 = 786432
    int i = idx & 31;
    int n = (idx >> 5) & 1023;
    int hd = idx >> 15;
    if (hd >= 24) return;
    if (hd >= HEADS + KVH) {       // packed v copy
        int h = hd - (HEADS + KVH);
        const float* src = qkv + (size_t)n * QKVD + (HEADS + KVH + h) * DH;
        float* dst = vr + ((size_t)h * NTOK + n) * DH;
        dst[2 * i] = src[2 * i];
        dst[2 * i + 1] = src[2 * i + 1];
        return;
    }
    float inv = powf(10000.f, -(float)i / 32.f);
    float fr = (float)n * inv;
    float c = cosf(fr), s = sinf(fr);
    const float* src; float* dst;
    if (hd < HEADS) { src = qkv + (size_t)n * QKVD + hd * DH;          dst = qr + ((size_t)hd * NTOK + n) * DH; }
    else { int h = hd - HEADS;
           src = qkv + (size_t)n * QKVD + (HEADS + h) * DH;            dst = kr + ((size_t)h * NTOK + n) * DH; }
    float x0 = src[2 * i], x1 = src[2 * i + 1];
    dst[2 * i]     = x0 * c - x1 * s;
    dst[2 * i + 1] = x1 * c + x0 * s;
}

// ---------------------------------------------------------------------------
// K8: compressed attention + importance + top-k. 4 tokens per 256-thr block.
// (unchanged — selection math must stay bit-identical)
// ---------------------------------------------------------------------------
__global__ __launch_bounds__(256)
void cattn_kernel(const float* __restrict__ qkv, const float* __restrict__ ck,
                  const float* __restrict__ cv, float* __restrict__ c_out,
                  int* __restrict__ sel, int* __restrict__ selmask) {
    int h = blockIdx.y;
    int tid = threadIdx.x;
    int w = tid >> 6, lane = tid & 63;
    int grp = lane >> 4, sub = lane & 15;
    int n = blockIdx.x * 4 + w;
    __shared__ float cks[33 * 68];
    __shared__ float cvs[33 * 68];
    __shared__ float sims[16 * 36];      // [w*4+g][j]

    for (int t4 = tid; t4 < 1056; t4 += 256) {
        int half = (t4 >= 528) ? 1 : 0;
        int u = t4 - half * 528;
        int j = u >> 4, d4 = (u & 15) * 4;
        const float* src = (half ? cv : ck) + (size_t)h * 33 * 64 + j * 64 + d4;
        float* dst = (half ? cvs : cks) + j * 68 + d4;
        *(float4*)dst = *(const float4*)src;
    }
    float qreg[64];
    {
        const float4* qp4 = (const float4*)(qkv + (size_t)n * QKVD + (h * GQ + grp) * DH);
#pragma unroll
        for (int c = 0; c < 16; ++c) {
            float4 v = qp4[c];
            qreg[4 * c] = v.x; qreg[4 * c + 1] = v.y; qreg[4 * c + 2] = v.z; qreg[4 * c + 3] = v.w;
        }
    }
    __syncthreads();

#pragma unroll
    for (int r = 0; r < 3; ++r) {
        int j = r * 16 + sub;
        if (j < 33) {
            float acc = 0.f;
#pragma unroll
            for (int d = 0; d < 64; ++d) acc = fmaf(qreg[d], cks[j * 68 + d], acc);
            sims[(w * 4 + grp) * 36 + j] = acc * SCALE;
        }
    }

    float ival = NEGINF;
    if (lane < 32)
        ival = 0.25f * (sims[(w * 4 + 0) * 36 + 1 + lane] + sims[(w * 4 + 1) * 36 + 1 + lane] +
                        sims[(w * 4 + 2) * 36 + 1 + lane] + sims[(w * 4 + 3) * 36 + 1 + lane]);
    float m = ival;
    for (int off = 32; off; off >>= 1) m = fmaxf(m, __shfl_xor(m, off));
    float e = (lane < 32) ? expf(ival - m) : 0.f;
    float sum = e;
    for (int off = 32; off; off >>= 1) sum += __shfl_xor(sum, off);
    float p = (lane < 32) ? e / sum : NEGINF;

    float v = p;
    int base = (h * NTOK + n) * 9;
    for (int t = 0; t < NSEL; ++t) {
        float bv = v; int bi = lane;
        for (int off = 32; off; off >>= 1) {
            float ov = __shfl_xor(bv, off);
            int   oi = __shfl_xor(bi, off);
            if (ov > bv || (ov == bv && oi < bi)) { bv = ov; bi = oi; }
        }
        if (lane == 0) { sel[base + t] = bi; selmask[base + t] = (bv > 1e-10f) ? 1 : 0; }
        if (lane == bi) v = NEGINF;
    }
    if (lane == 0) { sel[base + NSEL] = n >> 5; selmask[base + NSEL] = 1; }

#pragma unroll
    for (int g = 0; g < 4; ++g) {
        float sv = (lane < 33) ? sims[(w * 4 + g) * 36 + lane] : NEGINF;
        float mm = sv;
        for (int off = 32; off; off >>= 1) mm = fmaxf(mm, __shfl_xor(mm, off));
        float ee = (lane < 33) ? __expf(sv - mm) : 0.f;
        float ssum = ee;
        for (int off = 32; off; off >>= 1) ssum += __shfl_xor(ssum, off);
        if (lane < 33) sims[(w * 4 + g) * 36 + lane] = ee / ssum;
    }

    f32x4 o = (f32x4){0.f, 0.f, 0.f, 0.f};
#pragma unroll
    for (int j = 0; j < 33; ++j) {
        float a = sims[(w * 4 + grp) * 36 + j];
        f32x4 vv = *(const f32x4*)&cvs[j * 68 + sub * 4];
        o += a * vv;
    }
    *(f32x4*)&c_out[(((size_t)(h * GQ + grp)) * NTOK + n) * DH + sub * 4] = o;
}

// ---------------------------------------------------------------------------
// K9: fine attention v8 — v7 skeleton with:
//  (1) PV as f32x4/thread over wave j-slices (16 b128-bcast reads vs 64 b32),
//      cross-wave f32x4 reduce once at end (reuses KV buffer, no extra LDS);
//  (2) 4-accumulator ILP in the score dot;
//  (3) hoisted staging addresses + full bp unroll.
// Softmax/selection-relevant math bit-identical to v7.
// ---------------------------------------------------------------------------
__global__ __launch_bounds__(256, 8)
void fattn_kernel(const float* __restrict__ qr, const float* __restrict__ kr,
                  const float* __restrict__ vr, const int* __restrict__ sel,
                  const int* __restrict__ selmask, float* __restrict__ f_out) {
    int n = blockIdx.x, h = blockIdx.y;
    int tid = threadIdx.x;
    int w = tid >> 6, lane = tid & 63;
    int grp = lane >> 4, sub = lane & 15;
    __shared__ float qsm[4 * 68];
    __shared__ float KV[64 * 68];        // K, then V each pair; reused as reduce buf
    __shared__ float ssc[4 * 68];
    __shared__ float ps[4 * 68];
    __shared__ float alphas[4], ls[4];
    __shared__ int sel_s[9], msk_s[9];

    if (tid < 9) {
        sel_s[tid] = sel[(h * NTOK + n) * 9 + tid];
        msk_s[tid] = selmask[(h * NTOK + n) * 9 + tid];
    }
    qsm[w * 68 + lane] = qr[(((size_t)(h * GQ + w)) * NTOK + n) * DH + lane];
    f32x4 oA = (f32x4){0.f, 0.f, 0.f, 0.f};
    f32x4 oB = (f32x4){0.f, 0.f, 0.f, 0.f};
    float m_run = -3.402823466e38f, l_run = 0.f;
    __syncthreads();

    const float* krh_ = kr + (size_t)h * NTOK * DH;
    const float* vrh_ = vr + (size_t)h * NTOK * DH;
    int rowt = tid >> 4;           // 0..15 (staging row base)
    int d4s = (tid & 15) * 4;      // staging d offset

#pragma unroll
    for (int bp = 0; bp < 5; ++bp) {
        const int nrow = (bp < 4) ? 64 : 32;
        // ---- stage K (hoisted addressing: 2 base pointers per pair)
        {
            const float* b0 = krh_ + (size_t)sel_s[bp * 2] * (BSZ * DH);
            *(float4*)&KV[rowt * 68 + d4s]        = *(const float4*)&b0[rowt * DH + d4s];
            *(float4*)&KV[(rowt + 16) * 68 + d4s] = *(const float4*)&b0[(rowt + 16) * DH + d4s];
            if (nrow == 64) {
                const float* b1 = krh_ + (size_t)sel_s[bp * 2 + 1] * (BSZ * DH);
                *(float4*)&KV[(rowt + 32) * 68 + d4s] = *(const float4*)&b1[rowt * DH + d4s];
                *(float4*)&KV[(rowt + 48) * 68 + d4s] = *(const float4*)&b1[(rowt + 16) * DH + d4s];
            }
        }
        __syncthreads();                  // B1: K staged

        // ---- scores: (g=grp, jj=w*16+sub), 4 accumulators
        {
            int jj = w * 16 + sub;
            int b = bp * 2 + (jj >> 5);
            float s = -3.402823466e38f;
            if (jj < nrow && msk_s[b]) {
                float a0 = 0.f, a1 = 0.f, a2 = 0.f, a3 = 0.f;
#pragma unroll
                for (int c = 0; c < 4; ++c) {
                    f32x4 k0 = *(const f32x4*)&KV[jj * 68 + c * 16 + 0];
                    f32x4 q0 = *(const f32x4*)&qsm[grp * 68 + c * 16 + 0];
                    f32x4 k1 = *(const f32x4*)&KV[jj * 68 + c * 16 + 4];
                    f32x4 q1 = *(const f32x4*)&qsm[grp * 68 + c * 16 + 4];
                    f32x4 k2 = *(const f32x4*)&KV[jj * 68 + c * 16 + 8];
                    f32x4 q2 = *(const f32x4*)&qsm[grp * 68 + c * 16 + 8];
                    f32x4 k3 = *(const f32x4*)&KV[jj * 68 + c * 16 + 12];
                    f32x4 q3 = *(const f32x4*)&qsm[grp * 68 + c * 16 + 12];
                    a0 = fmaf(q0[0], k0[0], a0); a0 = fmaf(q0[1], k0[1], a0);
                    a0 = fmaf(q0[2], k0[2], a0); a0 = fmaf(q0[3], k0[3], a0);
                    a1 = fmaf(q1[0], k1[0], a1); a1 = fmaf(q1[1], k1[1], a1);
                    a1 = fmaf(q1[2], k1[2], a1); a1 = fmaf(q1[3], k1[3], a1);
                    a2 = fmaf(q2[0], k2[0], a2); a2 = fmaf(q2[1], k2[1], a2);
                    a2 = fmaf(q2[2], k2[2], a2); a2 = fmaf(q2[3], k2[3], a2);
                    a3 = fmaf(q3[0], k3[0], a3); a3 = fmaf(q3[1], k3[1], a3);
                    a3 = fmaf(q3[2], k3[2], a3); a3 = fmaf(q3[3], k3[3], a3);
                }
                s = ((a0 + a1) + (a2 + a3)) * SCALE;
            }
            ssc[grp * 68 + jj] = s;
        }
        __syncthreads();                  // B2: scores done, K reads done

        // ---- stage V (overwrite KV) + online softmax (wave w owns head w)
        {
            const float* b0 = vrh_ + (size_t)sel_s[bp * 2] * (BSZ * DH);
            *(float4*)&KV[rowt * 68 + d4s]        = *(const float4*)&b0[rowt * DH + d4s];
            *(float4*)&KV[(rowt + 16) * 68 + d4s] = *(const float4*)&b0[(rowt + 16) * DH + d4s];
            if (nrow == 64) {
                const float* b1 = vrh_ + (size_t)sel_s[bp * 2 + 1] * (BSZ * DH);
                *(float4*)&KV[(rowt + 32) * 68 + d4s] = *(const float4*)&b1[rowt * DH + d4s];
                *(float4*)&KV[(rowt + 48) * 68 + d4s] = *(const float4*)&b1[(rowt + 16) * DH + d4s];
            }
        }
        {
            float sv = ssc[w * 68 + lane];
            float mb = sv;
            for (int off = 32; off; off >>= 1) mb = fmaxf(mb, __shfl_xor(mb, off));
            float m_new = fmaxf(m_run, mb);
            float pp = (sv > -1e37f) ? __expf(sv - m_new) : 0.f;
            float alpha = __expf(m_run - m_new);
            float psum = pp;
            for (int off = 32; off; off >>= 1) psum += __shfl_xor(psum, off);
            l_run = l_run * alpha + psum;
            m_run = m_new;
            ps[w * 68 + lane] = pp;
            if (lane == 0) alphas[w] = alpha;
        }
        __syncthreads();                  // B3: V staged, ps/alphas ready

        // ---- PV: thread (grp, d4=sub*4) over wave's j-slice [w*16, w*16+16)
        {
            float alpha = alphas[grp];
            oA *= alpha;
            oB *= alpha;
#pragma unroll
            for (int t = 0; t < 8; ++t) {
                int jA = w * 16 + t;
                int jB = w * 16 + 8 + t;
                float pA = ps[grp * 68 + jA];
                float pB = ps[grp * 68 + jB];
                f32x4 vA = *(const f32x4*)&KV[jA * 68 + sub * 4];
                f32x4 vB = *(const f32x4*)&KV[jB * 68 + sub * 4];
                oA += pA * vA;
                oB += pB * vB;
            }
        }
        __syncthreads();                  // B4: PV's V reads done (KV free)
    }
    if (lane == 0) ls[w] = l_run;
    f32x4* red = (f32x4*)KV;              // reuse KV as the reduce buffer
    red[tid] = oA + oB;
    __syncthreads();
    if (w == 0) {
        f32x4 a = red[tid] + red[64 + tid] + red[128 + tid] + red[192 + tid];
        a *= (1.f / ls[grp]);
        *(f32x4*)&f_out[(((size_t)(h * GQ + grp)) * NTOK + n) * DH + sub * 4] = a;
    }
}

// ---------------------------------------------------------------------------
// K10: gated mix -> split-bf16 TILED (K=DDIM). gates f32 [N][128] padded.
// ---------------------------------------------------------------------------
__global__ void mix_kernel(const float* __restrict__ gates, const float* __restrict__ c_out,
                           const float* __restrict__ f_out,
                           u16* __restrict__ mixhi, u16* __restrict__ mixlo) {
    int idx = blockIdx.x * 256 + threadIdx.x;   // 1024*1024/8 = 131072
    int col = (idx & 127) * 8;
    int n = idx >> 7;
    int hd = col >> 6, d = col & 63;
    float g0 = gates[(size_t)n * 128 + hd * 2];
    float g1 = gates[(size_t)n * 128 + hd * 2 + 1];
    size_t hoff = (((size_t)hd) * NTOK + n) * DH + d;
    u16x8 h, l;
#pragma unroll
    for (int j = 0; j < 8; ++j) {
        float v = g0 * c_out[hoff + j] + g1 * f_out[hoff + j];
        u16 hh = f2bf(v);
        h[j] = hh;
        l[j] = f2bf(v - bf2f(hh));
    }
    size_t ob = tiled_off(n, col, DDIM);
    *(u16x8*)&mixhi[ob] = h;
    *(u16x8*)&mixlo[ob] = l;
}

// ---------------------------------------------------------------------------
extern "C" void kernel_launch(void* const* d_in, const int* in_sizes, int n_in,
                              void* d_out, int out_size, void* d_ws, size_t ws_size,
                              hipStream_t stream) {
    const float* inp    = (const float*)d_in[0];
    const float* g_norm = (const float*)d_in[1];
    const float* w_qkv  = (const float*)d_in[2];
    const float* mem_kv = (const float*)d_in[3];
    const float* k_pos  = (const float*)d_in[4];
    const float* v_pos  = (const float*)d_in[5];
    const float* k_w1   = (const float*)d_in[6];
    const float* k_b1   = (const float*)d_in[7];
    const float* k_w2   = (const float*)d_in[8];
    const float* k_b2   = (const float*)d_in[9];
    const float* v_w1   = (const float*)d_in[10];
    const float* v_b1   = (const float*)d_in[11];
    const float* v_w2   = (const float*)d_in[12];
    const float* v_b2   = (const float*)d_in[13];
    const float* gate_w = (const float*)d_in[14];
    const float* gate_b = (const float*)d_in[15];
    const float* w_out  = (const float*)d_in[16];
    float* out = (float*)d_out;

    char* wsb = (char*)d_ws;
    size_t off = 0;
    auto alloc = [&](size_t bytes) -> void* {
        void* p = wsb + off;
        off = (off + bytes + 255) & ~(size_t)255;
        return p;
    };
    u16*   xhi    = (u16*)  alloc((size_t)NTOK * DDIM * 2);
    u16*   xlo    = (u16*)  alloc((size_t)NTOK * DDIM * 2);
    float* qkvb   = (float*)alloc((size_t)NTOK * QKVD * 4);
    u16*   wqThi  = (u16*)  alloc((size_t)QKVD * DDIM * 2);
    u16*   wqTlo  = (u16*)  alloc((size_t)QKVD * DDIM * 2);
    u16*   kw1Thi = (u16*)  alloc((size_t)HIDN * CDIM * 2);
    u16*   kw1Tlo = (u16*)  alloc((size_t)HIDN * CDIM * 2);
    u16*   vw1Thi = (u16*)  alloc((size_t)HIDN * CDIM * 2);
    u16*   vw1Tlo = (u16*)  alloc((size_t)HIDN * CDIM * 2);
    u16*   woThi  = (u16*)  alloc((size_t)DDIM * DDIM * 2);
    u16*   gwThi  = (u16*)  alloc((size_t)128 * DDIM * 2);
    u16*   gwTlo  = (u16*)  alloc((size_t)128 * DDIM * 2);
    float* gbp    = (float*)alloc(128 * 4);
    u16*   kw2Thi = (u16*)  alloc((size_t)128 * HIDN * 2);
    u16*   kw2Tlo = (u16*)  alloc((size_t)128 * HIDN * 2);
    float* kb2p   = (float*)alloc(128 * 4);
    u16*   vw2Thi = (u16*)  alloc((size_t)128 * HIDN * 2);
    u16*   vw2Tlo = (u16*)  alloc((size_t)128 * HIDN * 2);
    float* vb2p   = (float*)alloc(128 * 4);
    u16*   cinkhi = (u16*)  alloc((size_t)128 * CDIM * 2);
    u16*   cinklo = (u16*)  alloc((size_t)128 * CDIM * 2);
    u16*   cinvhi = (u16*)  alloc((size_t)128 * CDIM * 2);
    u16*   cinvlo = (u16*)  alloc((size_t)128 * CDIM * 2);
    u16*   hidkhi = (u16*)  alloc((size_t)128 * HIDN * 2);
    u16*   hidklo = (u16*)  alloc((size_t)128 * HIDN * 2);
    u16*   hidvhi = (u16*)  alloc((size_t)128 * HIDN * 2);
    u16*   hidvlo = (u16*)  alloc((size_t)128 * HIDN * 2);
    float* Pg     = (float*)alloc((size_t)8 * NTOK * 128 * 4);
    float* Pm1k   = (float*)alloc((size_t)4 * 128 * HIDN * 4);
    float* Pm1v   = (float*)alloc((size_t)4 * 128 * HIDN * 4);
    float* Pm2k   = (float*)alloc((size_t)8 * 128 * 128 * 4);
    float* Pm2v   = (float*)alloc((size_t)8 * 128 * 128 * 4);
    float* ck     = (float*)alloc((size_t)KVH * 33 * DH * 4);
    float* cv     = (float*)alloc((size_t)KVH * 33 * DH * 4);
    float* qr     = (float*)alloc((size_t)HEADS * NTOK * DH * 4);
    float* kr     = (float*)alloc((size_t)KVH * NTOK * DH * 4);
    float* vr     = (float*)alloc((size_t)KVH * NTOK * DH * 4);
    float* c_out  = (float*)alloc((size_t)HEADS * NTOK * DH * 4);
    float* f_out  = (float*)alloc((size_t)HEADS * NTOK * DH * 4);
    float* gates  = (float*)alloc((size_t)NTOK * 128 * 4);
    int*   sel    = (int*)  alloc((size_t)KVH * NTOK * 9 * 4);
    int*   selmask= (int*)  alloc((size_t)KVH * NTOK * 9 * 4);
    u16*   mixhi  = (u16*)  alloc((size_t)NTOK * DDIM * 2);
    u16*   mixlo  = (u16*)  alloc((size_t)NTOK * DDIM * 2);

    // weight prep: 4 transposes in ONE launch, 3 pads in ONE launch
    prep_weights<<<2688, 256, 0, stream>>>(w_qkv, wqThi, wqTlo,
                                           k_w1, kw1Thi, kw1Tlo,
                                           v_w1, vw1Thi, vw1Tlo,
                                           w_out, woThi);
    pad_all<<<dim3(128, 3), 256, 0, stream>>>(gate_w, gate_b, gwThi, gwTlo, gbp,
                                              k_w2, k_b2, kw2Thi, kw2Tlo, kb2p,
                                              v_w2, v_b2, vw2Thi, vw2Tlo, vb2p);

    // 1. RMSNorm -> tiled split-bf16 x
    rmsnorm_kernel<<<NTOK / 2, 256, 0, stream>>>(inp, g_norm, xhi, xlo);
    // 2. qkv = x @ w_qkv (final f32)
    gemm_tiled<3, 0, 1><<<dim3(QKVD / 128, NTOK / 128, 1), 256, 0, stream>>>(
        xhi, xlo, wqThi, wqTlo, nullptr, qkvb,
        xhi, xlo, wqThi, wqTlo, nullptr, qkvb, NTOK, QKVD, DDIM, 1);
    // 3. gates (split-K 8 + sigmoid reduce)
    gemm_tiled<3, 0, 0><<<dim3(1, NTOK / 128, 8), 256, 0, stream>>>(
        xhi, xlo, gwThi, gwTlo, nullptr, Pg,
        xhi, xlo, gwThi, gwTlo, nullptr, Pg, NTOK, 128, DDIM, 8);
    reduce_f32<2><<<dim3(128, 1), 256, 0, stream>>>(Pg, gbp, gates, Pg, gbp, gates, 8, NTOK, 128);
    // 4. compress-MLP inputs (tiled)
    build_cmlp_in<<<128, 256, 0, stream>>>(qkvb, k_pos, v_pos, cinkhi, cinklo, cinvhi, cinvlo);
    // 5. MLP1 (split-K 4, k&v batched; relu+bias+split-tile in reduce)
    gemm_tiled<3, 0, 0><<<dim3(HIDN / 128, 1, 8), 256, 0, stream>>>(
        cinkhi, cinklo, kw1Thi, kw1Tlo, nullptr, Pm1k,
        cinvhi, cinvlo, vw1Thi, vw1Tlo, nullptr, Pm1v, 128, HIDN, CDIM, 4);
    reduce_hid<<<dim3(128, 2), 256, 0, stream>>>(Pm1k, k_b1, hidkhi, hidklo,
                                                 Pm1v, v_b1, hidvhi, hidvlo, 4);
    // 6. MLP2 (split-K 8, k&v batched) + fused reduce/bias/concat
    gemm_tiled<3, 0, 0><<<dim3(1, 1, 16), 256, 0, stream>>>(
        hidkhi, hidklo, kw2Thi, kw2Tlo, nullptr, Pm2k,
        hidvhi, hidvlo, vw2Thi, vw2Tlo, nullptr, Pm2v, 128, 128, HIDN, 8);
    reduce_ckcv<<<33, 256, 0, stream>>>(Pm2k, Pm2v, mem_kv, kb2p, vb2p, ck, cv, 8);
    // 8. rotary + packed v
    rotary_kernel<<<(24 * NTOK * 32) / 256, 256, 0, stream>>>(qkvb, qr, kr, vr);
    // 9. compressed attention + selection (4 tokens per block)
    cattn_kernel<<<dim3(NTOK / 4, KVH), 256, 0, stream>>>(qkvb, ck, cv, c_out, sel, selmask);
    // 10. fine attention (v8: light PV, ILP score, hoisted staging)
    fattn_kernel<<<dim3(NTOK, KVH), 256, 0, stream>>>(qr, kr, vr, sel, selmask, f_out);
    // 11. gated mix -> tiled split-bf16
    mix_kernel<<<(NTOK * DDIM / 8) / 256, 256, 0, stream>>>(gates, c_out, f_out, mixhi, mixlo);
    // 12. output projection (bf16, final)
    gemm_tiled<1, 0, 1><<<dim3(DDIM / 128, NTOK / 128, 1), 256, 0, stream>>>(
        mixhi, mixhi, woThi, woThi, nullptr, out,
        mixhi, mixhi, woThi, woThi, nullptr, out, NTOK, DDIM, DDIM, 1);
}